// Round 3
// baseline (9702.168 us; speedup 1.0000x reference)
//
#include <hip/hip_runtime.h>
#include <cstdint>
#include <cstddef>

#define ZB 512
#define ZT 256
#define ZIN 64
#define ZEH 128
#define ZH 512
#define ZG 2048
#define ZNC 8
#define NBLK 256

typedef __attribute__((ext_vector_type(8))) short s8v;
typedef __attribute__((ext_vector_type(4))) float f4v;
typedef unsigned short u16;
typedef unsigned int u32;

__device__ __forceinline__ u16 f2bf(float f){
  u32 u = __builtin_bit_cast(u32, f);
  u += 0x7FFFu + ((u >> 16) & 1u);
  return (u16)(u >> 16);
}

// ---------------------------------------------------------------------------
// Fold: Wc[2048][128] = W_ih @ W2 (bf16), bc[2048] = W_ih@b2 + b_ih + b_hh
// ---------------------------------------------------------------------------
__global__ __launch_bounds__(128)
void k_fold(const float* __restrict__ W_ih, const float* __restrict__ W2,
            const float* __restrict__ b2, const float* __restrict__ b_ih,
            const float* __restrict__ b_hh, u16* __restrict__ Wc,
            float* __restrict__ bc)
{
  const int r = blockIdx.x, c = threadIdx.x;
  const float* wr = W_ih + (size_t)r * ZH;
  float acc = 0.f;
  for (int k = 0; k < ZH; ++k) acc += wr[k] * W2[(size_t)k * ZEH + c];
  Wc[(size_t)r * ZEH + c] = f2bf(acc);
  __shared__ float red[128];
  float p = 0.f;
  for (int k = c; k < ZH; k += 128) p += wr[k] * b2[k];
  red[c] = p; __syncthreads();
  for (int s = 64; s > 0; s >>= 1){ if (c < s) red[c] += red[c + s]; __syncthreads(); }
  if (c == 0) bc[r] = red[0] + b_ih[r] + b_hh[r];
}

// ---------------------------------------------------------------------------
// f32 -> bf16 cast
// ---------------------------------------------------------------------------
__global__ __launch_bounds__(256)
void k_cvt(const float* __restrict__ src, u16* __restrict__ dst, int n)
{
  int i = blockIdx.x * 256 + threadIdx.x;
  if (i < n) dst[i] = f2bf(src[i]);
}

// ---------------------------------------------------------------------------
// Encoder layer 1: X1[B*T][128] = bf16(LeakyReLU(seq @ W1^T + b1))
// ---------------------------------------------------------------------------
__global__ __launch_bounds__(256)
void k_enc(const float* __restrict__ seq, const float* __restrict__ W1,
           const float* __restrict__ b1, u16* __restrict__ X1)
{
  __shared__ float w1s[ZEH * 65];
  __shared__ float sqs[64 * 65];
  const int tid = threadIdx.x;
  const size_t rb = (size_t)blockIdx.x * 64;
  for (int i = tid; i < ZEH * ZIN; i += 256){ int r = i >> 6, c = i & 63; w1s[r * 65 + c] = W1[i]; }
  for (int i = tid; i < 64 * ZIN; i += 256){ int r = i >> 6, c = i & 63; sqs[r * 65 + c] = seq[(rb + r) * ZIN + c]; }
  __syncthreads();
  const int cg = tid & 31, rg = tid >> 5;
  float acc[8][4];
  #pragma unroll
  for (int i = 0; i < 8; ++i){
    #pragma unroll
    for (int j = 0; j < 4; ++j) acc[i][j] = 0.f;
  }
  for (int k = 0; k < ZIN; ++k){
    float wv[4], sv[8];
    #pragma unroll
    for (int j = 0; j < 4; ++j) wv[j] = w1s[(cg * 4 + j) * 65 + k];
    #pragma unroll
    for (int i = 0; i < 8; ++i) sv[i] = sqs[(rg * 8 + i) * 65 + k];
    #pragma unroll
    for (int i = 0; i < 8; ++i){
      #pragma unroll
      for (int j = 0; j < 4; ++j) acc[i][j] += sv[i] * wv[j];
    }
  }
  #pragma unroll
  for (int i = 0; i < 8; ++i){
    ushort4 pk;
    float v0 = acc[i][0] + b1[cg * 4 + 0]; v0 = v0 > 0.f ? v0 : 0.01f * v0;
    float v1 = acc[i][1] + b1[cg * 4 + 1]; v1 = v1 > 0.f ? v1 : 0.01f * v1;
    float v2 = acc[i][2] + b1[cg * 4 + 2]; v2 = v2 > 0.f ? v2 : 0.01f * v2;
    float v3 = acc[i][3] + b1[cg * 4 + 3]; v3 = v3 > 0.f ? v3 : 0.01f * v3;
    pk.x = f2bf(v0); pk.y = f2bf(v1); pk.z = f2bf(v2); pk.w = f2bf(v3);
    *(ushort4*)(X1 + (rb + rg * 8 + i) * ZEH + cg * 4) = pk;
  }
}

// ---------------------------------------------------------------------------
// group-local barrier wait: 32 flags (one per hg block of this bg), one per
// lane, 64B-padded, read-only polling (no RMW). All waves call this.
// ---------------------------------------------------------------------------
__device__ __forceinline__ void group_wait(const u32* flags, int bg, u32 target)
{
  const int l = threadIdx.x & 63;
  const u32* fp = flags + ((size_t)(bg * 32 + (l & 31))) * 16;
  long long guard = 0;
  for (;;){
    u32 v = __hip_atomic_load(fp, __ATOMIC_RELAXED, __HIP_MEMORY_SCOPE_AGENT);
    if (__ballot(v >= target) == ~0ull) break;
    __builtin_amdgcn_s_sleep(1);
    if (++guard > (1LL << 22)) break;   // fail loud (wrong answer), never hang
  }
}

// ---------------------------------------------------------------------------
// Cooperative LSTM over all T=256 steps.
// 256 blocks = 8 batch-groups (64 rows) x 32 hcol-groups (16 h-cols).
// W_hh slice + folded Wc slice live in registers for the whole kernel.
// h exchanged via double-buffered global hbuf + per-bg 32-block flag barrier.
// ---------------------------------------------------------------------------
__global__ __launch_bounds__(256, 2)
void k_lstm(const u16* __restrict__ X1, const u16* __restrict__ Whh,
            const u16* __restrict__ Wcf, const float* __restrict__ bc,
            const u16* __restrict__ Wfcb, const float* __restrict__ bfc,
            u16* __restrict__ hbuf, float* __restrict__ out,
            u32* __restrict__ flags)
{
  __shared__ u16 hs[64 * ZH];   // 64 KiB, XOR-swizzled h tile
  const int tid = threadIdx.x;
  const int w = tid >> 6, l = tid & 63;
  const int lr = l & 15, lg = l >> 4;
  const int bg = (int)blockIdx.x >> 5, hg = (int)blockIdx.x & 31;
  const int gt = lr >> 2;
  const int grow = gt * ZH + hg * 16 + w * 4 + (lr & 3);  // gate row in [0,2048)

  // persistent B-operand fragments (W_hh slice: 64 VGPR, Wc slice: 16 VGPR)
  s8v bwh[16], bwx[4];
  {
    const u16* p = Whh + (size_t)grow * ZH + lg * 8;
    #pragma unroll
    for (int kt = 0; kt < 16; ++kt) bwh[kt] = *(const s8v*)(p + kt * 32);
    const u16* q = Wcf + (size_t)grow * ZEH + lg * 8;
    #pragma unroll
    for (int kt = 0; kt < 4; ++kt) bwx[kt] = *(const s8v*)(q + kt * 32);
  }
  const float bias = bc[grow];

  float c_reg[4][4];
  #pragma unroll
  for (int a = 0; a < 4; ++a){
    #pragma unroll
    for (int b = 0; b < 4; ++b) c_reg[a][b] = 0.f;
  }

  const u16* xbase[4];
  #pragma unroll
  for (int mt = 0; mt < 4; ++mt)
    xbase[mt] = X1 + (size_t)(bg * 64 + mt * 16 + lr) * (ZT * ZEH) + lg * 8;

  const int hcb = hg * 16 + w * 4;
  u32* myflag = flags + ((size_t)(bg * 32 + hg)) * 16;

  for (int t = 0; t < ZT; ++t){
    // prefetch this step's x fragments (independent of the barrier) so their
    // HBM latency hides under the flag wait
    s8v ax[4][4];
    #pragma unroll
    for (int mt = 0; mt < 4; ++mt){
      const u16* xp = xbase[mt] + (size_t)t * ZEH;
      #pragma unroll
      for (int kt = 0; kt < 4; ++kt) ax[mt][kt] = *(const s8v*)(xp + kt * 32);
    }

    if (t > 0){
      group_wait(flags, bg, (u32)t);   // h_t fully visible
      __threadfence();                  // acquire: invalidate L1/L2
    }

    // stage h_t tile [64][512] bf16 into swizzled LDS (coalesced 16B)
    const u16* hsrc = hbuf + (size_t)(t & 1) * (ZB * ZH) + (size_t)bg * 64 * ZH;
    #pragma unroll
    for (int i = 0; i < 16; ++i){
      int c = tid + i * 256;        // 16B chunk; one wave instr = one row
      int byte = c * 16;
      int row = byte >> 10;
      s8v v = *(const s8v*)(hsrc + (size_t)c * 8);
      *(s8v*)((char*)hs + (byte ^ ((row & 7) << 4))) = v;
    }
    __syncthreads();

    u16* hdst = hbuf + (size_t)((t + 1) & 1) * (ZB * ZH);
    #pragma unroll
    for (int mt = 0; mt < 4; ++mt){
      f4v acc = {bias, bias, bias, bias};
      #pragma unroll
      for (int kt = 0; kt < 16; ++kt){
        int row = mt * 16 + lr;
        int byte = row * (ZH * 2) + kt * 64 + lg * 16;
        s8v av = *(const s8v*)((char*)hs + (byte ^ ((row & 7) << 4)));
        acc = __builtin_amdgcn_mfma_f32_16x16x32_bf16(av, bwh[kt], acc, 0, 0, 0);
      }
      #pragma unroll
      for (int kt = 0; kt < 4; ++kt)
        acc = __builtin_amdgcn_mfma_f32_16x16x32_bf16(ax[mt][kt], bwx[kt], acc, 0, 0, 0);

      // LSTM cell: i-gate lanes gather f,g,o via shfl_xor (gate stride 4 lanes)
      #pragma unroll
      for (int r = 0; r < 4; ++r){
        float v = acc[r];
        float s = (gt == 2) ? 2.f : -1.f;
        float e = __expf(v * s);
        float rc = 1.f / (1.f + e);
        float a = (gt == 2) ? (1.f - 2.f * rc) : rc;   // tanh : sigmoid
        float f_ = __shfl_xor(a, 4);
        float g_ = __shfl_xor(a, 8);
        float o_ = __shfl_xor(a, 12);
        float cv = f_ * c_reg[mt][r] + a * g_;
        c_reg[mt][r] = cv;
        float e2 = __expf(2.f * cv);
        float hv = o_ * (1.f - 2.f / (1.f + e2));
        u32 bits = f2bf(hv);
        u32 lo = bits | (((u32)__shfl_xor((int)bits, 1)) << 16);
        u32 hi = (u32)__shfl_xor((int)lo, 2);
        if (lr == 0){
          int rrow = bg * 64 + mt * 16 + lg * 4 + r;
          uint2 pk; pk.x = lo; pk.y = hi;
          *(uint2*)(hdst + (size_t)rrow * ZH + hcb) = pk;   // 4 h-cols, 8B
        }
      }
    }

    __syncthreads();                    // all h stores issued & complete
    if (tid == 0){
      __threadfence();                  // release: flush this CU's stores
      __hip_atomic_store(myflag, (u32)(t + 1), __ATOMIC_RELAXED, __HIP_MEMORY_SCOPE_AGENT);
    }
  }

  // epilogue: hg==0 blocks compute out = h_T @ Wfc^T + bfc  (h_T is in hbuf[0])
  if (hg == 0){
    group_wait(flags, bg, (u32)ZT);
    __threadfence();
    float ob = (lr < ZNC) ? bfc[lr] : 0.f;
    f4v acc = {ob, ob, ob, ob};
    const u16* hp = hbuf + (size_t)(bg * 64 + w * 16 + lr) * ZH + lg * 8;
    const u16* wp = Wfcb + (size_t)lr * ZH + lg * 8;
    #pragma unroll
    for (int kt = 0; kt < 16; ++kt){
      s8v av = *(const s8v*)(hp + kt * 32);
      s8v bv = *(const s8v*)(wp + kt * 32);
      acc = __builtin_amdgcn_mfma_f32_16x16x32_bf16(av, bv, acc, 0, 0, 0);
    }
    if (lr < ZNC){
      #pragma unroll
      for (int r = 0; r < 4; ++r)
        out[(size_t)(bg * 64 + w * 16 + lg * 4 + r) * ZNC + lr] = acc[r];
    }
  }
}

// ---------------------------------------------------------------------------
extern "C" void kernel_launch(void* const* d_in, const int* in_sizes, int n_in,
                              void* d_out, int out_size, void* d_ws, size_t ws_size,
                              hipStream_t stream)
{
  const float* seq  = (const float*)d_in[0];
  const float* W1   = (const float*)d_in[1];
  const float* b1   = (const float*)d_in[2];
  const float* W2   = (const float*)d_in[3];
  const float* b2   = (const float*)d_in[4];
  const float* W_ih = (const float*)d_in[5];
  const float* W_hh = (const float*)d_in[6];
  const float* b_ih = (const float*)d_in[7];
  const float* b_hh = (const float*)d_in[8];
  const float* Wfc  = (const float*)d_in[9];
  const float* bfc  = (const float*)d_in[10];
  float* out = (float*)d_out;

  char* ws = (char*)d_ws;
  size_t off = 0;
  auto alloc = [&](size_t bytes){ void* p = ws + off; off += (bytes + 255) & ~(size_t)255; return p; };
  u16*   Wc    = (u16*)  alloc((size_t)ZG * ZEH * 2);
  float* bc    = (float*)alloc((size_t)ZG * 4);
  u16*   Whh   = (u16*)  alloc((size_t)ZG * ZH * 2);
  u16*   Wfcb  = (u16*)  alloc((size_t)16 * ZH * 2);
  u16*   X1    = (u16*)  alloc((size_t)ZB * ZT * ZEH * 2);
  u16*   hbuf  = (u16*)  alloc((size_t)2 * ZB * ZH * 2);
  u32*   flags = (u32*)  alloc((size_t)8 * 32 * 16 * 4);   // 64B-padded per-block flags

  hipMemsetAsync(flags, 0, (size_t)8 * 32 * 16 * 4, stream);
  hipMemsetAsync(hbuf, 0, (size_t)ZB * ZH * 2, stream);      // h_0 = 0 (buffer 0)
  hipMemsetAsync(Wfcb, 0, (size_t)16 * ZH * 2, stream);      // pad rows 8..15 = 0

  hipLaunchKernelGGL(k_fold, dim3(ZG), dim3(128), 0, stream, W_ih, W2, b2, b_ih, b_hh, Wc, bc);
  hipLaunchKernelGGL(k_cvt, dim3((ZG * ZH + 255) / 256), dim3(256), 0, stream, W_hh, Whh, ZG * ZH);
  hipLaunchKernelGGL(k_cvt, dim3((ZNC * ZH + 255) / 256), dim3(256), 0, stream, Wfc, Wfcb, ZNC * ZH);
  hipLaunchKernelGGL(k_enc, dim3(ZB * ZT / 64), dim3(256), 0, stream, seq, W1, b1, X1);
  hipLaunchKernelGGL(k_lstm, dim3(NBLK), dim3(256), 0, stream,
                     X1, Whh, Wc, bc, Wfcb, bfc, hbuf, out, flags);
}

// Round 4
// 4264.534 us; speedup vs baseline: 2.2751x; 2.2751x over previous
//
#include <hip/hip_runtime.h>
#include <cstdint>
#include <cstddef>

#define ZB 512
#define ZT 256
#define ZIN 64
#define ZEH 128
#define ZH 512
#define ZG 2048
#define ZNC 8
#define NBLK 256

typedef __attribute__((ext_vector_type(8))) short s8v;
typedef __attribute__((ext_vector_type(4))) float f4v;
typedef unsigned short u16;
typedef unsigned int u32;
typedef unsigned long long u64;

__device__ __forceinline__ u16 f2bf(float f){
  u32 u = __builtin_bit_cast(u32, f);
  u += 0x7FFFu + ((u >> 16) & 1u);
  return (u16)(u >> 16);
}
__device__ __forceinline__ s8v pair2v(u64 a, u64 b){
  union { u64 q[2]; s8v v; } u; u.q[0] = a; u.q[1] = b; return u.v;
}

// ---------------------------------------------------------------------------
// Fold: Wc[2048][128] = W_ih @ W2 (bf16), bc[2048] = W_ih@b2 + b_ih + b_hh
// ---------------------------------------------------------------------------
__global__ __launch_bounds__(128)
void k_fold(const float* __restrict__ W_ih, const float* __restrict__ W2,
            const float* __restrict__ b2, const float* __restrict__ b_ih,
            const float* __restrict__ b_hh, u16* __restrict__ Wc,
            float* __restrict__ bc)
{
  const int r = blockIdx.x, c = threadIdx.x;
  const float* wr = W_ih + (size_t)r * ZH;
  float acc = 0.f;
  for (int k = 0; k < ZH; ++k) acc += wr[k] * W2[(size_t)k * ZEH + c];
  Wc[(size_t)r * ZEH + c] = f2bf(acc);
  __shared__ float red[128];
  float p = 0.f;
  for (int k = c; k < ZH; k += 128) p += wr[k] * b2[k];
  red[c] = p; __syncthreads();
  for (int s = 64; s > 0; s >>= 1){ if (c < s) red[c] += red[c + s]; __syncthreads(); }
  if (c == 0) bc[r] = red[0] + b_ih[r] + b_hh[r];
}

// ---------------------------------------------------------------------------
// f32 -> bf16 cast
// ---------------------------------------------------------------------------
__global__ __launch_bounds__(256)
void k_cvt(const float* __restrict__ src, u16* __restrict__ dst, int n)
{
  int i = blockIdx.x * 256 + threadIdx.x;
  if (i < n) dst[i] = f2bf(src[i]);
}

// ---------------------------------------------------------------------------
// Encoder layer 1: X1[B*T][128] = bf16(LeakyReLU(seq @ W1^T + b1))
// ---------------------------------------------------------------------------
__global__ __launch_bounds__(256)
void k_enc(const float* __restrict__ seq, const float* __restrict__ W1,
           const float* __restrict__ b1, u16* __restrict__ X1)
{
  __shared__ float w1s[ZEH * 65];
  __shared__ float sqs[64 * 65];
  const int tid = threadIdx.x;
  const size_t rb = (size_t)blockIdx.x * 64;
  for (int i = tid; i < ZEH * ZIN; i += 256){ int r = i >> 6, c = i & 63; w1s[r * 65 + c] = W1[i]; }
  for (int i = tid; i < 64 * ZIN; i += 256){ int r = i >> 6, c = i & 63; sqs[r * 65 + c] = seq[(rb + r) * ZIN + c]; }
  __syncthreads();
  const int cg = tid & 31, rg = tid >> 5;
  float acc[8][4];
  #pragma unroll
  for (int i = 0; i < 8; ++i){
    #pragma unroll
    for (int j = 0; j < 4; ++j) acc[i][j] = 0.f;
  }
  for (int k = 0; k < ZIN; ++k){
    float wv[4], sv[8];
    #pragma unroll
    for (int j = 0; j < 4; ++j) wv[j] = w1s[(cg * 4 + j) * 65 + k];
    #pragma unroll
    for (int i = 0; i < 8; ++i) sv[i] = sqs[(rg * 8 + i) * 65 + k];
    #pragma unroll
    for (int i = 0; i < 8; ++i){
      #pragma unroll
      for (int j = 0; j < 4; ++j) acc[i][j] += sv[i] * wv[j];
    }
  }
  #pragma unroll
  for (int i = 0; i < 8; ++i){
    ushort4 pk;
    float v0 = acc[i][0] + b1[cg * 4 + 0]; v0 = v0 > 0.f ? v0 : 0.01f * v0;
    float v1 = acc[i][1] + b1[cg * 4 + 1]; v1 = v1 > 0.f ? v1 : 0.01f * v1;
    float v2 = acc[i][2] + b1[cg * 4 + 2]; v2 = v2 > 0.f ? v2 : 0.01f * v2;
    float v3 = acc[i][3] + b1[cg * 4 + 3]; v3 = v3 > 0.f ? v3 : 0.01f * v3;
    pk.x = f2bf(v0); pk.y = f2bf(v1); pk.z = f2bf(v2); pk.w = f2bf(v3);
    *(ushort4*)(X1 + (rb + rg * 8 + i) * ZEH + cg * 4) = pk;
  }
}

// ---------------------------------------------------------------------------
// group wait: called by wave 0 only. Lane l polls flag (l&31) of this bg via
// agent-scope (MALL-coherent, L2-bypass) loads; exit when all 32 >= target.
// ---------------------------------------------------------------------------
__device__ __forceinline__ void group_wait(const u32* flags, int bg, u32 target)
{
  const int l = threadIdx.x & 63;
  const u32* fp = flags + ((size_t)(bg * 32 + (l & 31))) * 16;
  long long guard = 0;
  for (;;){
    u32 v = __hip_atomic_load(fp, __ATOMIC_RELAXED, __HIP_MEMORY_SCOPE_AGENT);
    if (__ballot(v >= target) == ~0ull) break;
    __builtin_amdgcn_s_sleep(2);
    if (++guard > (1LL << 19)) break;   // fail loud (wrong answer), never hang
  }
}

// ---------------------------------------------------------------------------
// Cooperative LSTM over all T=256 steps.
// 256 blocks = 8 batch-groups (64 rows) x 32 hcol-groups (16 h-cols).
// W_hh slice + folded Wc slice live in registers for the whole kernel.
// h and flags move exclusively via agent-scope (sc1 / MALL-coherent) atomics:
// NO threadfence anywhere -> no per-step L2 writeback/invalidate storms.
// Release = s_waitcnt vmcnt(0) + syncthreads + flag store.
// Acquire = flag poll (sc1) ; data loads are sc1 so nothing stale is visible.
// ---------------------------------------------------------------------------
__global__ __launch_bounds__(256, 2)
void k_lstm(const u16* __restrict__ X1, const u16* __restrict__ Whh,
            const u16* __restrict__ Wcf, const float* __restrict__ bc,
            const u16* __restrict__ Wfcb, const float* __restrict__ bfc,
            u16* __restrict__ hbuf, float* __restrict__ out,
            u32* __restrict__ flags)
{
  __shared__ u16 hs[64 * ZH];   // 64 KiB, XOR-swizzled h tile
  const int tid = threadIdx.x;
  const int w = tid >> 6, l = tid & 63;
  const int lr = l & 15, lg = l >> 4;
  const int bg = (int)blockIdx.x >> 5, hg = (int)blockIdx.x & 31;
  const int gt = lr >> 2;
  const int grow = gt * ZH + hg * 16 + w * 4 + (lr & 3);  // gate row in [0,2048)

  // persistent B-operand fragments (W_hh slice: 64 VGPR, Wc slice: 16 VGPR)
  s8v bwh[16], bwx[4];
  {
    const u16* p = Whh + (size_t)grow * ZH + lg * 8;
    #pragma unroll
    for (int kt = 0; kt < 16; ++kt) bwh[kt] = *(const s8v*)(p + kt * 32);
    const u16* q = Wcf + (size_t)grow * ZEH + lg * 8;
    #pragma unroll
    for (int kt = 0; kt < 4; ++kt) bwx[kt] = *(const s8v*)(q + kt * 32);
  }
  const float bias = bc[grow];

  float c_reg[4][4];
  #pragma unroll
  for (int a = 0; a < 4; ++a){
    #pragma unroll
    for (int b = 0; b < 4; ++b) c_reg[a][b] = 0.f;
  }

  const u16* xbase[4];
  #pragma unroll
  for (int mt = 0; mt < 4; ++mt)
    xbase[mt] = X1 + (size_t)(bg * 64 + mt * 16 + lr) * (ZT * ZEH) + lg * 8;

  const int hcb = hg * 16 + w * 4;
  u32* myflag = flags + ((size_t)(bg * 32 + hg)) * 16;

  for (int t = 0; t < ZT; ++t){
    // prefetch this step's x fragments (cached loads, hidden under the wait)
    s8v ax[4][4];
    #pragma unroll
    for (int mt = 0; mt < 4; ++mt){
      const u16* xp = xbase[mt] + (size_t)t * ZEH;
      #pragma unroll
      for (int kt = 0; kt < 4; ++kt) ax[mt][kt] = *(const s8v*)(xp + kt * 32);
    }

    if (t > 0){
      if (tid < 64) group_wait(flags, bg, (u32)t);   // wave 0 polls
      __syncthreads();                               // releases other waves
    }

    // stage h_t [64][512] bf16 -> swizzled LDS via agent-scope (sc1) loads;
    // two-phase (issue 16 loads, then LDS-write) for memory-level parallelism
    const u64* hsrc = (const u64*)(hbuf + (size_t)(t & 1) * (ZB * ZH)) +
                      (size_t)bg * 64 * (ZH / 4);
    #pragma unroll
    for (int half = 0; half < 2; ++half){
      u64 va[8], vb[8];
      #pragma unroll
      for (int i = 0; i < 8; ++i){
        int c = tid + (half * 8 + i) * 256;          // 16B chunk id
        va[i] = __hip_atomic_load(hsrc + (size_t)c * 2,     __ATOMIC_RELAXED, __HIP_MEMORY_SCOPE_AGENT);
        vb[i] = __hip_atomic_load(hsrc + (size_t)c * 2 + 1, __ATOMIC_RELAXED, __HIP_MEMORY_SCOPE_AGENT);
      }
      #pragma unroll
      for (int i = 0; i < 8; ++i){
        int c = tid + (half * 8 + i) * 256;
        int byte = c * 16, row = byte >> 10;
        char* p = (char*)hs + (byte ^ ((row & 7) << 4));
        *(u64*)p = va[i];
        *(u64*)(p + 8) = vb[i];
      }
    }
    __syncthreads();

    u16* hdst = hbuf + (size_t)((t + 1) & 1) * (ZB * ZH);
    #pragma unroll
    for (int mt = 0; mt < 4; ++mt){
      f4v acc = {bias, bias, bias, bias};
      #pragma unroll
      for (int kt = 0; kt < 16; ++kt){
        int row = mt * 16 + lr;
        int byte = row * (ZH * 2) + kt * 64 + lg * 16;
        s8v av = *(const s8v*)((char*)hs + (byte ^ ((row & 7) << 4)));
        acc = __builtin_amdgcn_mfma_f32_16x16x32_bf16(av, bwh[kt], acc, 0, 0, 0);
      }
      #pragma unroll
      for (int kt = 0; kt < 4; ++kt)
        acc = __builtin_amdgcn_mfma_f32_16x16x32_bf16(ax[mt][kt], bwx[kt], acc, 0, 0, 0);

      // LSTM cell: i-gate lanes gather f,g,o via shfl_xor (gate stride 4 lanes)
      #pragma unroll
      for (int r = 0; r < 4; ++r){
        float v = acc[r];
        float s = (gt == 2) ? 2.f : -1.f;
        float e = __expf(v * s);
        float rc = 1.f / (1.f + e);
        float a = (gt == 2) ? (1.f - 2.f * rc) : rc;   // tanh : sigmoid
        float f_ = __shfl_xor(a, 4);
        float g_ = __shfl_xor(a, 8);
        float o_ = __shfl_xor(a, 12);
        float cv = f_ * c_reg[mt][r] + a * g_;
        c_reg[mt][r] = cv;
        float e2 = __expf(2.f * cv);
        float hv = o_ * (1.f - 2.f / (1.f + e2));
        u32 bits = f2bf(hv);
        u32 lo = bits | (((u32)__shfl_xor((int)bits, 1)) << 16);
        u32 hi = (u32)__shfl_xor((int)lo, 2);
        if (lr == 0){
          int rrow = bg * 64 + mt * 16 + lg * 4 + r;
          u64 pk = (u64)lo | ((u64)hi << 32);
          __hip_atomic_store((u64*)(hdst + (size_t)rrow * ZH + hcb), pk,
                             __ATOMIC_RELAXED, __HIP_MEMORY_SCOPE_AGENT);
        }
      }
    }

    // release: sc1 stores complete (acked at coherence point), then flag
    asm volatile("s_waitcnt vmcnt(0)" ::: "memory");
    __syncthreads();
    if (tid == 0)
      __hip_atomic_store(myflag, (u32)(t + 1), __ATOMIC_RELAXED, __HIP_MEMORY_SCOPE_AGENT);
  }

  // epilogue: hg==0 blocks compute out = h_T @ Wfc^T + bfc  (h_T in hbuf[0])
  if (hg == 0){
    if (tid < 64) group_wait(flags, bg, (u32)ZT);
    __syncthreads();
    float ob = (lr < ZNC) ? bfc[lr] : 0.f;
    f4v acc = {ob, ob, ob, ob};
    const u64* hp = (const u64*)hbuf + (size_t)(bg * 64 + w * 16 + lr) * (ZH / 4);
    const u16* wp = Wfcb + (size_t)lr * ZH + lg * 8;
    #pragma unroll
    for (int kt = 0; kt < 16; ++kt){
      u64 a0 = __hip_atomic_load(hp + kt * 8 + lg * 2,     __ATOMIC_RELAXED, __HIP_MEMORY_SCOPE_AGENT);
      u64 a1 = __hip_atomic_load(hp + kt * 8 + lg * 2 + 1, __ATOMIC_RELAXED, __HIP_MEMORY_SCOPE_AGENT);
      s8v av = pair2v(a0, a1);
      s8v bv = *(const s8v*)(wp + kt * 32);
      acc = __builtin_amdgcn_mfma_f32_16x16x32_bf16(av, bv, acc, 0, 0, 0);
    }
    if (lr < ZNC){
      #pragma unroll
      for (int r = 0; r < 4; ++r)
        out[(size_t)(bg * 64 + w * 16 + lg * 4 + r) * ZNC + lr] = acc[r];
    }
  }
}

// ---------------------------------------------------------------------------
extern "C" void kernel_launch(void* const* d_in, const int* in_sizes, int n_in,
                              void* d_out, int out_size, void* d_ws, size_t ws_size,
                              hipStream_t stream)
{
  const float* seq  = (const float*)d_in[0];
  const float* W1   = (const float*)d_in[1];
  const float* b1   = (const float*)d_in[2];
  const float* W2   = (const float*)d_in[3];
  const float* b2   = (const float*)d_in[4];
  const float* W_ih = (const float*)d_in[5];
  const float* W_hh = (const float*)d_in[6];
  const float* b_ih = (const float*)d_in[7];
  const float* b_hh = (const float*)d_in[8];
  const float* Wfc  = (const float*)d_in[9];
  const float* bfc  = (const float*)d_in[10];
  float* out = (float*)d_out;

  char* ws = (char*)d_ws;
  size_t off = 0;
  auto alloc = [&](size_t bytes){ void* p = ws + off; off += (bytes + 255) & ~(size_t)255; return p; };
  u16*   Wc    = (u16*)  alloc((size_t)ZG * ZEH * 2);
  float* bc    = (float*)alloc((size_t)ZG * 4);
  u16*   Whh   = (u16*)  alloc((size_t)ZG * ZH * 2);
  u16*   Wfcb  = (u16*)  alloc((size_t)16 * ZH * 2);
  u16*   X1    = (u16*)  alloc((size_t)ZB * ZT * ZEH * 2);
  u16*   hbuf  = (u16*)  alloc((size_t)2 * ZB * ZH * 2);
  u32*   flags = (u32*)  alloc((size_t)8 * 32 * 16 * 4);   // 64B-padded per-block flags

  hipMemsetAsync(flags, 0, (size_t)8 * 32 * 16 * 4, stream);
  hipMemsetAsync(hbuf, 0, (size_t)ZB * ZH * 2, stream);      // h_0 = 0 (buffer 0)
  hipMemsetAsync(Wfcb, 0, (size_t)16 * ZH * 2, stream);      // pad rows 8..15 = 0

  hipLaunchKernelGGL(k_fold, dim3(ZG), dim3(128), 0, stream, W_ih, W2, b2, b_ih, b_hh, Wc, bc);
  hipLaunchKernelGGL(k_cvt, dim3((ZG * ZH + 255) / 256), dim3(256), 0, stream, W_hh, Whh, ZG * ZH);
  hipLaunchKernelGGL(k_cvt, dim3((ZNC * ZH + 255) / 256), dim3(256), 0, stream, Wfc, Wfcb, ZNC * ZH);
  hipLaunchKernelGGL(k_enc, dim3(ZB * ZT / 64), dim3(256), 0, stream, seq, W1, b1, X1);
  hipLaunchKernelGGL(k_lstm, dim3(NBLK), dim3(256), 0, stream,
                     X1, Whh, Wc, bc, Wfcb, bfc, hbuf, out, flags);
}

// Round 5
// 3075.197 us; speedup vs baseline: 3.1550x; 1.3868x over previous
//
#include <hip/hip_runtime.h>
#include <cstdint>
#include <cstddef>

#define ZB 512
#define ZT 256
#define ZIN 64
#define ZEH 128
#define ZH 512
#define ZG 2048
#define ZNC 8
#define NBLK 256

typedef __attribute__((ext_vector_type(8))) short s8v;
typedef __attribute__((ext_vector_type(4))) float f4v;
typedef unsigned short u16;
typedef unsigned int u32;
typedef unsigned long long u64;

__device__ __forceinline__ u16 f2bf(float f){
  u32 u = __builtin_bit_cast(u32, f);
  u += 0x7FFFu + ((u >> 16) & 1u);
  return (u16)(u >> 16);
}
__device__ __forceinline__ s8v pair2v(u64 a, u64 b){
  union { u64 q[2]; s8v v; } u; u.q[0] = a; u.q[1] = b; return u.v;
}
// h layout: [buf][bg][mt][hg][16 rows][16 cols] u16; chunk = 512B contiguous
__device__ __forceinline__ size_t qoff(int buf, int bg, int mt, int hg){
  return ((((size_t)buf * 8 + bg) * 4 + mt) * 32 + hg) * 256;
}

// ---------------------------------------------------------------------------
// Fold: Wc[2048][128] = W_ih @ W2 (bf16), bc[2048] = W_ih@b2 + b_ih + b_hh
// ---------------------------------------------------------------------------
__global__ __launch_bounds__(128)
void k_fold(const float* __restrict__ W_ih, const float* __restrict__ W2,
            const float* __restrict__ b2, const float* __restrict__ b_ih,
            const float* __restrict__ b_hh, u16* __restrict__ Wc,
            float* __restrict__ bc)
{
  const int r = blockIdx.x, c = threadIdx.x;
  const float* wr = W_ih + (size_t)r * ZH;
  float acc = 0.f;
  for (int k = 0; k < ZH; ++k) acc += wr[k] * W2[(size_t)k * ZEH + c];
  Wc[(size_t)r * ZEH + c] = f2bf(acc);
  __shared__ float red[128];
  float p = 0.f;
  for (int k = c; k < ZH; k += 128) p += wr[k] * b2[k];
  red[c] = p; __syncthreads();
  for (int s = 64; s > 0; s >>= 1){ if (c < s) red[c] += red[c + s]; __syncthreads(); }
  if (c == 0) bc[r] = red[0] + b_ih[r] + b_hh[r];
}

// ---------------------------------------------------------------------------
// f32 -> bf16 cast
// ---------------------------------------------------------------------------
__global__ __launch_bounds__(256)
void k_cvt(const float* __restrict__ src, u16* __restrict__ dst, int n)
{
  int i = blockIdx.x * 256 + threadIdx.x;
  if (i < n) dst[i] = f2bf(src[i]);
}

// ---------------------------------------------------------------------------
// Encoder layer 1: X1[B*T][128] = bf16(LeakyReLU(seq @ W1^T + b1))
// ---------------------------------------------------------------------------
__global__ __launch_bounds__(256)
void k_enc(const float* __restrict__ seq, const float* __restrict__ W1,
           const float* __restrict__ b1, u16* __restrict__ X1)
{
  __shared__ float w1s[ZEH * 65];
  __shared__ float sqs[64 * 65];
  const int tid = threadIdx.x;
  const size_t rb = (size_t)blockIdx.x * 64;
  for (int i = tid; i < ZEH * ZIN; i += 256){ int r = i >> 6, c = i & 63; w1s[r * 65 + c] = W1[i]; }
  for (int i = tid; i < 64 * ZIN; i += 256){ int r = i >> 6, c = i & 63; sqs[r * 65 + c] = seq[(rb + r) * ZIN + c]; }
  __syncthreads();
  const int cg = tid & 31, rg = tid >> 5;
  float acc[8][4];
  #pragma unroll
  for (int i = 0; i < 8; ++i){
    #pragma unroll
    for (int j = 0; j < 4; ++j) acc[i][j] = 0.f;
  }
  for (int k = 0; k < ZIN; ++k){
    float wv[4], sv[8];
    #pragma unroll
    for (int j = 0; j < 4; ++j) wv[j] = w1s[(cg * 4 + j) * 65 + k];
    #pragma unroll
    for (int i = 0; i < 8; ++i) sv[i] = sqs[(rg * 8 + i) * 65 + k];
    #pragma unroll
    for (int i = 0; i < 8; ++i){
      #pragma unroll
      for (int j = 0; j < 4; ++j) acc[i][j] += sv[i] * wv[j];
    }
  }
  #pragma unroll
  for (int i = 0; i < 8; ++i){
    ushort4 pk;
    float v0 = acc[i][0] + b1[cg * 4 + 0]; v0 = v0 > 0.f ? v0 : 0.01f * v0;
    float v1 = acc[i][1] + b1[cg * 4 + 1]; v1 = v1 > 0.f ? v1 : 0.01f * v1;
    float v2 = acc[i][2] + b1[cg * 4 + 2]; v2 = v2 > 0.f ? v2 : 0.01f * v2;
    float v3 = acc[i][3] + b1[cg * 4 + 3]; v3 = v3 > 0.f ? v3 : 0.01f * v3;
    pk.x = f2bf(v0); pk.y = f2bf(v1); pk.z = f2bf(v2); pk.w = f2bf(v3);
    *(ushort4*)(X1 + (rb + rg * 8 + i) * ZEH + cg * 4) = pk;
  }
}

// ---------------------------------------------------------------------------
// quarter wait: wave 0 only; lane l polls flag[bg][mt][l&31] (agent scope).
// ---------------------------------------------------------------------------
__device__ __forceinline__ void qwait(const u32* flags, int bg, int mt, u32 target)
{
  const int l = threadIdx.x & 63;
  const u32* fp = flags + ((size_t)((bg * 4 + mt) * 32 + (l & 31))) * 16;
  long long guard = 0;
  for (;;){
    u32 v = __hip_atomic_load(fp, __ATOMIC_RELAXED, __HIP_MEMORY_SCOPE_AGENT);
    if (__ballot(v >= target) == ~0ull) break;
    __builtin_amdgcn_s_sleep(1);
    if (++guard > (1LL << 20)) break;   // fail loud (wrong answer), never hang
  }
}

// ---------------------------------------------------------------------------
// Cooperative LSTM, T=256 steps, each step split into 4 batch-quarters that
// form 4 independent sync pipelines: quarter (t+1,mt) needs only (t,mt) of
// the 32 blocks sharing bg. A block publishes (t,mt) ~3 quarter-durations
// before consumers need it -> sync latency hidden under other quarters' work.
// 256 blocks = 8 bg x 32 hg. W_hh + folded-Wc slices in registers. All h /
// flag traffic via agent-scope (MALL) accesses; no threadfence anywhere.
// ---------------------------------------------------------------------------
__global__ __launch_bounds__(256, 1)
void k_lstm(const u16* __restrict__ X1, const u16* __restrict__ Whh,
            const u16* __restrict__ Wcf, const float* __restrict__ bc,
            const u16* __restrict__ Wfcb, const float* __restrict__ bfc,
            u16* __restrict__ hbuf, float* __restrict__ out,
            u32* __restrict__ flags)
{
  __shared__ u16 hs[16 * ZH];   // 16 KiB quarter tile, XOR-swizzled
  const int tid = threadIdx.x;
  const int w = tid >> 6, l = tid & 63;
  const int lr = l & 15, lg = l >> 4;
  const int bg = (int)blockIdx.x >> 5, hg = (int)blockIdx.x & 31;
  const int gt = lr >> 2;
  const int grow = gt * ZH + hg * 16 + w * 4 + (lr & 3);  // gate row in [0,2048)

  // persistent B fragments: W_hh slice 64 VGPR, Wc slice 16 VGPR
  s8v bwh[16], bwx[4];
  {
    const u16* p = Whh + (size_t)grow * ZH + lg * 8;
    #pragma unroll
    for (int kt = 0; kt < 16; ++kt) bwh[kt] = *(const s8v*)(p + kt * 32);
    const u16* q = Wcf + (size_t)grow * ZEH + lg * 8;
    #pragma unroll
    for (int kt = 0; kt < 4; ++kt) bwx[kt] = *(const s8v*)(q + kt * 32);
  }
  const float bias = bc[grow];

  float c_reg[4][4];
  #pragma unroll
  for (int a = 0; a < 4; ++a){
    #pragma unroll
    for (int b = 0; b < 4; ++b) c_reg[a][b] = 0.f;
  }

  u32* myflag0 = flags + ((size_t)(bg * 4 * 32 + hg)) * 16;

  for (int t = 0; t < ZT; ++t){
    #pragma unroll
    for (int mt = 0; mt < 4; ++mt){
      // x fragments for this quarter (cached loads, issued before the wait)
      const u16* xp = X1 + ((size_t)((bg * 64 + mt * 16 + lr) * ZT + t)) * ZEH + lg * 8;
      s8v ax0 = *(const s8v*)(xp);
      s8v ax1 = *(const s8v*)(xp + 32);
      s8v ax2 = *(const s8v*)(xp + 64);
      s8v ax3 = *(const s8v*)(xp + 96);

      if (tid < 64) qwait(flags, bg, mt, (u32)t);
      __syncthreads();

      // stage quarter tile [16 rows][512 cols] = 16KB, fully coalesced
      {
        const u64* src = (const u64*)(hbuf + qoff(t & 1, bg, mt, 0));
        u64 va[4], vb[4];
        #pragma unroll
        for (int i = 0; i < 4; ++i){
          int cc = tid + i * 256;
          va[i] = __hip_atomic_load(src + (size_t)cc * 2,     __ATOMIC_RELAXED, __HIP_MEMORY_SCOPE_AGENT);
          vb[i] = __hip_atomic_load(src + (size_t)cc * 2 + 1, __ATOMIC_RELAXED, __HIP_MEMORY_SCOPE_AGENT);
        }
        #pragma unroll
        for (int i = 0; i < 4; ++i){
          int byte = (tid + i * 256) * 16;
          int swz = byte ^ (((byte >> 5) & 3) << 4);
          *(s8v*)((char*)hs + swz) = pair2v(va[i], vb[i]);
        }
      }
      __syncthreads();

      // 16 recurrent + 4 input MFMAs into one 16x16 tile
      f4v acc = {bias, bias, bias, bias};
      #pragma unroll
      for (int kt = 0; kt < 16; ++kt){
        int byte = (2 * kt + (lg >> 1)) * 512 + lr * 32 + (lg & 1) * 16;
        byte ^= ((lr & 3) << 4);
        s8v av = *(const s8v*)((char*)hs + byte);
        acc = __builtin_amdgcn_mfma_f32_16x16x32_bf16(av, bwh[kt], acc, 0, 0, 0);
      }
      acc = __builtin_amdgcn_mfma_f32_16x16x32_bf16(ax0, bwx[0], acc, 0, 0, 0);
      acc = __builtin_amdgcn_mfma_f32_16x16x32_bf16(ax1, bwx[1], acc, 0, 0, 0);
      acc = __builtin_amdgcn_mfma_f32_16x16x32_bf16(ax2, bwx[2], acc, 0, 0, 0);
      acc = __builtin_amdgcn_mfma_f32_16x16x32_bf16(ax3, bwx[3], acc, 0, 0, 0);

      // LSTM cell; gather f,g,o across gate lanes (stride 4)
      u16* hdst = hbuf + qoff((t + 1) & 1, bg, mt, hg);
      #pragma unroll
      for (int r = 0; r < 4; ++r){
        float v = acc[r];
        float s = (gt == 2) ? 2.f : -1.f;
        float e = __expf(v * s);
        float rc = 1.f / (1.f + e);
        float a = (gt == 2) ? (1.f - 2.f * rc) : rc;   // tanh : sigmoid
        float f_ = __shfl_xor(a, 4);
        float g_ = __shfl_xor(a, 8);
        float o_ = __shfl_xor(a, 12);
        float cv = f_ * c_reg[mt][r] + a * g_;
        c_reg[mt][r] = cv;
        float e2 = __expf(2.f * cv);
        float hv = o_ * (1.f - 2.f / (1.f + e2));
        u32 bits = f2bf(hv);
        u32 lo = bits | (((u32)__shfl_xor((int)bits, 1)) << 16);
        u32 hi = (u32)__shfl_xor((int)lo, 2);
        if (lr == 0){
          // chunk-local: row = lg*4+r (32B stride), cols w*4..w*4+3 (8B)
          u64 pk = (u64)lo | ((u64)hi << 32);
          __hip_atomic_store((u64*)(hdst + (size_t)(lg * 4 + r) * 16 + w * 4), pk,
                             __ATOMIC_RELAXED, __HIP_MEMORY_SCOPE_AGENT);
        }
      }

      // release: h stores acked at MALL, then publish quarter flag
      asm volatile("s_waitcnt vmcnt(0)" ::: "memory");
      __syncthreads();
      if (tid == 0)
        __hip_atomic_store(myflag0 + (size_t)mt * 32 * 16, (u32)(t + 1),
                           __ATOMIC_RELAXED, __HIP_MEMORY_SCOPE_AGENT);
    }
  }

  // epilogue: hg==0 blocks compute out = h_T @ Wfc^T + bfc (h_T in buf 0)
  if (hg == 0){
    if (tid < 64){
      #pragma unroll
      for (int mt = 0; mt < 4; ++mt) qwait(flags, bg, mt, (u32)ZT);
    }
    __syncthreads();
    float ob = (lr < ZNC) ? bfc[lr] : 0.f;
    f4v acc = {ob, ob, ob, ob};
    const u16* wp = Wfcb + (size_t)lr * ZH + lg * 8;
    #pragma unroll
    for (int kt = 0; kt < 16; ++kt){
      int hgp = 2 * kt + (lg >> 1);
      const u64* hp = (const u64*)(hbuf + qoff(0, bg, w, hgp));
      u64 a0 = __hip_atomic_load(hp + lr * 4 + (lg & 1) * 2,     __ATOMIC_RELAXED, __HIP_MEMORY_SCOPE_AGENT);
      u64 a1 = __hip_atomic_load(hp + lr * 4 + (lg & 1) * 2 + 1, __ATOMIC_RELAXED, __HIP_MEMORY_SCOPE_AGENT);
      s8v av = pair2v(a0, a1);
      s8v bv = *(const s8v*)(wp + kt * 32);
      acc = __builtin_amdgcn_mfma_f32_16x16x32_bf16(av, bv, acc, 0, 0, 0);
    }
    if (lr < ZNC){
      #pragma unroll
      for (int r = 0; r < 4; ++r)
        out[(size_t)(bg * 64 + w * 16 + lg * 4 + r) * ZNC + lr] = acc[r];
    }
  }
}

// ---------------------------------------------------------------------------
extern "C" void kernel_launch(void* const* d_in, const int* in_sizes, int n_in,
                              void* d_out, int out_size, void* d_ws, size_t ws_size,
                              hipStream_t stream)
{
  const float* seq  = (const float*)d_in[0];
  const float* W1   = (const float*)d_in[1];
  const float* b1   = (const float*)d_in[2];
  const float* W2   = (const float*)d_in[3];
  const float* b2   = (const float*)d_in[4];
  const float* W_ih = (const float*)d_in[5];
  const float* W_hh = (const float*)d_in[6];
  const float* b_ih = (const float*)d_in[7];
  const float* b_hh = (const float*)d_in[8];
  const float* Wfc  = (const float*)d_in[9];
  const float* bfc  = (const float*)d_in[10];
  float* out = (float*)d_out;

  char* ws = (char*)d_ws;
  size_t off = 0;
  auto alloc = [&](size_t bytes){ void* p = ws + off; off += (bytes + 255) & ~(size_t)255; return p; };
  u16*   Wc    = (u16*)  alloc((size_t)ZG * ZEH * 2);
  float* bc    = (float*)alloc((size_t)ZG * 4);
  u16*   Whh   = (u16*)  alloc((size_t)ZG * ZH * 2);
  u16*   Wfcb  = (u16*)  alloc((size_t)16 * ZH * 2);
  u16*   X1    = (u16*)  alloc((size_t)ZB * ZT * ZEH * 2);
  u16*   hbuf  = (u16*)  alloc((size_t)2 * ZB * ZH * 2);
  u32*   flags = (u32*)  alloc((size_t)8 * 4 * 32 * 16 * 4);  // 64B-padded per (bg,mt,hg)

  hipMemsetAsync(flags, 0, (size_t)8 * 4 * 32 * 16 * 4, stream);
  hipMemsetAsync(hbuf, 0, (size_t)ZB * ZH * 2, stream);      // h_0 = 0 (buffer 0)
  hipMemsetAsync(Wfcb, 0, (size_t)16 * ZH * 2, stream);      // pad rows 8..15 = 0

  hipLaunchKernelGGL(k_fold, dim3(ZG), dim3(128), 0, stream, W_ih, W2, b2, b_ih, b_hh, Wc, bc);
  hipLaunchKernelGGL(k_cvt, dim3((ZG * ZH + 255) / 256), dim3(256), 0, stream, W_hh, Whh, ZG * ZH);
  hipLaunchKernelGGL(k_cvt, dim3((ZNC * ZH + 255) / 256), dim3(256), 0, stream, Wfc, Wfcb, ZNC * ZH);
  hipLaunchKernelGGL(k_enc, dim3(ZB * ZT / 64), dim3(256), 0, stream, seq, W1, b1, X1);
  hipLaunchKernelGGL(k_lstm, dim3(NBLK), dim3(256), 0, stream,
                     X1, Whh, Wc, bc, Wfcb, bfc, hbuf, out, flags);
}

// Round 6
// 2502.493 us; speedup vs baseline: 3.8770x; 1.2289x over previous
//
#include <hip/hip_runtime.h>
#include <cstdint>
#include <cstddef>

#define ZB 512
#define ZT 256
#define ZIN 64
#define ZEH 128
#define ZH 512
#define ZG 2048
#define ZNC 8
#define NBLK 256

typedef __attribute__((ext_vector_type(8))) short s8v;
typedef __attribute__((ext_vector_type(4))) float f4v;
typedef unsigned short u16;
typedef unsigned int u32;
typedef unsigned long long u64;

__device__ __forceinline__ u16 f2bf(float f){
  u32 u = __builtin_bit_cast(u32, f);
  u += 0x7FFFu + ((u >> 16) & 1u);
  return (u16)(u >> 16);
}
__device__ __forceinline__ s8v pair2v(u64 a, u64 b){
  union { u64 q[2]; s8v v; } u; u.q[0] = a; u.q[1] = b; return u.v;
}
// h layout: [buf][bg][mt][hg][16 rows][16 cols] u16; chunk = 512B contiguous
__device__ __forceinline__ size_t qoff(int buf, int bg, int mt, int hg){
  return ((((size_t)buf * 8 + bg) * 4 + mt) * 32 + hg) * 256;
}
__device__ __forceinline__ u64 aload(const u64* p){
  return __hip_atomic_load(p, __ATOMIC_RELAXED, __HIP_MEMORY_SCOPE_AGENT);
}

// ---------------------------------------------------------------------------
// Fold: Wc[2048][128] = W_ih @ W2 (bf16), bc[2048] = W_ih@b2 + b_ih + b_hh
// ---------------------------------------------------------------------------
__global__ __launch_bounds__(128)
void k_fold(const float* __restrict__ W_ih, const float* __restrict__ W2,
            const float* __restrict__ b2, const float* __restrict__ b_ih,
            const float* __restrict__ b_hh, u16* __restrict__ Wc,
            float* __restrict__ bc)
{
  const int r = blockIdx.x, c = threadIdx.x;
  const float* wr = W_ih + (size_t)r * ZH;
  float acc = 0.f;
  for (int k = 0; k < ZH; ++k) acc += wr[k] * W2[(size_t)k * ZEH + c];
  Wc[(size_t)r * ZEH + c] = f2bf(acc);
  __shared__ float red[128];
  float p = 0.f;
  for (int k = c; k < ZH; k += 128) p += wr[k] * b2[k];
  red[c] = p; __syncthreads();
  for (int s = 64; s > 0; s >>= 1){ if (c < s) red[c] += red[c + s]; __syncthreads(); }
  if (c == 0) bc[r] = red[0] + b_ih[r] + b_hh[r];
}

// ---------------------------------------------------------------------------
// f32 -> bf16 cast
// ---------------------------------------------------------------------------
__global__ __launch_bounds__(256)
void k_cvt(const float* __restrict__ src, u16* __restrict__ dst, int n)
{
  int i = blockIdx.x * 256 + threadIdx.x;
  if (i < n) dst[i] = f2bf(src[i]);
}

// ---------------------------------------------------------------------------
// Encoder layer 1: X1 (t-major: [T][B][128]) = bf16(LeakyReLU(seq@W1^T+b1))
// ---------------------------------------------------------------------------
__global__ __launch_bounds__(256)
void k_enc(const float* __restrict__ seq, const float* __restrict__ W1,
           const float* __restrict__ b1, u16* __restrict__ X1)
{
  __shared__ float w1s[ZEH * 65];
  __shared__ float sqs[64 * 65];
  const int tid = threadIdx.x;
  const size_t rb = (size_t)blockIdx.x * 64;
  for (int i = tid; i < ZEH * ZIN; i += 256){ int r = i >> 6, c = i & 63; w1s[r * 65 + c] = W1[i]; }
  for (int i = tid; i < 64 * ZIN; i += 256){ int r = i >> 6, c = i & 63; sqs[r * 65 + c] = seq[(rb + r) * ZIN + c]; }
  __syncthreads();
  const int cg = tid & 31, rg = tid >> 5;
  float acc[8][4];
  #pragma unroll
  for (int i = 0; i < 8; ++i){
    #pragma unroll
    for (int j = 0; j < 4; ++j) acc[i][j] = 0.f;
  }
  for (int k = 0; k < ZIN; ++k){
    float wv[4], sv[8];
    #pragma unroll
    for (int j = 0; j < 4; ++j) wv[j] = w1s[(cg * 4 + j) * 65 + k];
    #pragma unroll
    for (int i = 0; i < 8; ++i) sv[i] = sqs[(rg * 8 + i) * 65 + k];
    #pragma unroll
    for (int i = 0; i < 8; ++i){
      #pragma unroll
      for (int j = 0; j < 4; ++j) acc[i][j] += sv[i] * wv[j];
    }
  }
  #pragma unroll
  for (int i = 0; i < 8; ++i){
    ushort4 pk;
    float v0 = acc[i][0] + b1[cg * 4 + 0]; v0 = v0 > 0.f ? v0 : 0.01f * v0;
    float v1 = acc[i][1] + b1[cg * 4 + 1]; v1 = v1 > 0.f ? v1 : 0.01f * v1;
    float v2 = acc[i][2] + b1[cg * 4 + 2]; v2 = v2 > 0.f ? v2 : 0.01f * v2;
    float v3 = acc[i][3] + b1[cg * 4 + 3]; v3 = v3 > 0.f ? v3 : 0.01f * v3;
    pk.x = f2bf(v0); pk.y = f2bf(v1); pk.z = f2bf(v2); pk.w = f2bf(v3);
    int rf = (int)rb + rg * 8 + i;            // flat b*T + t
    int b = rf >> 8, tt = rf & 255;
    *(ushort4*)(X1 + ((size_t)tt * ZB + b) * ZEH + cg * 4) = pk;
  }
}

// ---------------------------------------------------------------------------
// quarter wait: lane l polls flag[bg][mt][l&31] (agent scope / MALL).
// ---------------------------------------------------------------------------
__device__ __forceinline__ void qwait(const u32* flags, int bg, int mt, u32 target)
{
  const int l = threadIdx.x & 63;
  const u32* fp = flags + ((size_t)((bg * 4 + mt) * 32 + (l & 31))) * 16;
  long long guard = 0;
  for (;;){
    u32 v = __hip_atomic_load(fp, __ATOMIC_RELAXED, __HIP_MEMORY_SCOPE_AGENT);
    if (__ballot(v >= target) == ~0ull) break;
    __builtin_amdgcn_s_sleep(1);
    if (++guard > (1LL << 20)) break;   // fail loud (wrong answer), never hang
  }
}

// ---------------------------------------------------------------------------
// Cooperative LSTM, wave-specialized. 256 blocks = 8 bg x 32 hg, 512 thr:
//   waves 0-3 (tid<256): compute — W_hh/Wc slices in regs, MFMA + cell + h-store
//   waves 4-7: stage    — at slot s: qwait+issue MALL loads for slot s+2,
//                         ds_write slot s+1's regs into the idle LDS half
// One barrier per slot. Flag slack = 2 slots hides store-ack + poll + load
// latency. No threadfence anywhere (all cross-block data via agent-scope ops).
// ---------------------------------------------------------------------------
__global__ __launch_bounds__(512, 1)
void k_lstm(const u16* __restrict__ X1, const u16* __restrict__ Whh,
            const u16* __restrict__ Wcf, const float* __restrict__ bc,
            const u16* __restrict__ Wfcb, const float* __restrict__ bfc,
            u16* __restrict__ hbuf, float* __restrict__ out,
            u32* __restrict__ flags)
{
  __shared__ u16 hs2[2][16 * ZH];   // 2 x 16 KiB, XOR-swizzled quarter tiles
  const int tid = threadIdx.x;
  const int bg = (int)blockIdx.x >> 5, hg = (int)blockIdx.x & 31;
  const bool isC = (tid < 256);
  const int w = (tid >> 6) & 3, l = tid & 63;
  const int lr = l & 15, lg = l >> 4;
  const int st = tid & 255;
  const int gt = lr >> 2;

  // ---- compute-role persistent state ----
  s8v bwh[16], bwx[4];
  f4v biasv = {0.f, 0.f, 0.f, 0.f};
  float c_reg[4][4];
  if (isC){
    const int grow = gt * ZH + hg * 16 + w * 4 + (lr & 3);
    const u16* p = Whh + (size_t)grow * ZH + lg * 8;
    #pragma unroll
    for (int kt = 0; kt < 16; ++kt) bwh[kt] = *(const s8v*)(p + kt * 32);
    const u16* q = Wcf + (size_t)grow * ZEH + lg * 8;
    #pragma unroll
    for (int kt = 0; kt < 4; ++kt) bwx[kt] = *(const s8v*)(q + kt * 32);
    float b = bc[grow];
    biasv[0] = b; biasv[1] = b; biasv[2] = b; biasv[3] = b;
    #pragma unroll
    for (int a = 0; a < 4; ++a){
      #pragma unroll
      for (int bq = 0; bq < 4; ++bq) c_reg[a][bq] = 0.f;
    }
  }

  // ---- stage-role prologue: slot0 -> E (write to buf0 now), slot1 -> O ----
  u64 vaE[4], vbE[4], vaO[4], vbO[4];
  if (!isC){
    const u64* s0 = (const u64*)(hbuf + qoff(0, bg, 0, 0));
    const u64* s1 = (const u64*)(hbuf + qoff(0, bg, 1, 0));
    #pragma unroll
    for (int i = 0; i < 4; ++i){
      int cc = st + i * 256;
      vaE[i] = aload(s0 + (size_t)cc * 2); vbE[i] = aload(s0 + (size_t)cc * 2 + 1);
      vaO[i] = aload(s1 + (size_t)cc * 2); vbO[i] = aload(s1 + (size_t)cc * 2 + 1);
    }
    #pragma unroll
    for (int i = 0; i < 4; ++i){
      int byte = (st + i * 256) * 16;
      int swz = byte ^ (((byte >> 5) & 3) << 4);
      *(s8v*)((char*)hs2[0] + swz) = pair2v(vaE[i], vbE[i]);
    }
  }
  __syncthreads();

  u32* fl0 = flags + ((size_t)(bg * 4 * 32 + hg)) * 16;

  for (int t = 0; t < ZT; ++t){
    #pragma unroll
    for (int mt = 0; mt < 4; ++mt){
      if (isC){
        // X fragments for THIS slot (L2-cached; latency hides under h-chain)
        const u16* xp = X1 + ((size_t)t * ZB + (bg * 64 + mt * 16 + lr)) * ZEH + lg * 8;
        s8v ax0 = *(const s8v*)(xp);
        s8v ax1 = *(const s8v*)(xp + 32);
        s8v ax2 = *(const s8v*)(xp + 64);
        s8v ax3 = *(const s8v*)(xp + 96);

        // two independent MFMA chains over the h tile
        f4v a0 = biasv;
        f4v a1 = {0.f, 0.f, 0.f, 0.f};
        const char* hb = (const char*)hs2[mt & 1];
        #pragma unroll
        for (int kt = 0; kt < 8; ++kt){
          int byte = (2 * kt + (lg >> 1)) * 512 + lr * 32 + (lg & 1) * 16;
          byte ^= ((lr & 3) << 4);
          s8v av = *(const s8v*)(hb + byte);
          a0 = __builtin_amdgcn_mfma_f32_16x16x32_bf16(av, bwh[kt], a0, 0, 0, 0);
        }
        #pragma unroll
        for (int kt = 8; kt < 16; ++kt){
          int byte = (2 * kt + (lg >> 1)) * 512 + lr * 32 + (lg & 1) * 16;
          byte ^= ((lr & 3) << 4);
          s8v av = *(const s8v*)(hb + byte);
          a1 = __builtin_amdgcn_mfma_f32_16x16x32_bf16(av, bwh[kt], a1, 0, 0, 0);
        }
        a0 = __builtin_amdgcn_mfma_f32_16x16x32_bf16(ax0, bwx[0], a0, 0, 0, 0);
        a1 = __builtin_amdgcn_mfma_f32_16x16x32_bf16(ax1, bwx[1], a1, 0, 0, 0);
        a0 = __builtin_amdgcn_mfma_f32_16x16x32_bf16(ax2, bwx[2], a0, 0, 0, 0);
        a1 = __builtin_amdgcn_mfma_f32_16x16x32_bf16(ax3, bwx[3], a1, 0, 0, 0);
        f4v acc = a0 + a1;

        // LSTM cell; gather f,g,o across gate lanes (stride 4)
        u16* hdst = hbuf + qoff((t + 1) & 1, bg, mt, hg);
        #pragma unroll
        for (int r = 0; r < 4; ++r){
          float v = acc[r];
          float s = (gt == 2) ? 2.f : -1.f;
          float e = __expf(v * s);
          float rc = 1.f / (1.f + e);
          float a = (gt == 2) ? (1.f - 2.f * rc) : rc;   // tanh : sigmoid
          float f_ = __shfl_xor(a, 4);
          float g_ = __shfl_xor(a, 8);
          float o_ = __shfl_xor(a, 12);
          float cv = f_ * c_reg[mt][r] + a * g_;
          c_reg[mt][r] = cv;
          float e2 = __expf(2.f * cv);
          float hv = o_ * (1.f - 2.f / (1.f + e2));
          u32 bits = f2bf(hv);
          u32 lo = bits | (((u32)__shfl_xor((int)bits, 1)) << 16);
          u32 hi = (u32)__shfl_xor((int)lo, 2);
          if (lr == 0){
            u64 pk = (u64)lo | ((u64)hi << 32);
            __hip_atomic_store((u64*)(hdst + (size_t)(lg * 4 + r) * 16 + w * 4), pk,
                               __ATOMIC_RELAXED, __HIP_MEMORY_SCOPE_AGENT);
          }
        }
        // own stores acked at MALL before the slot barrier -> flag publish safe
        asm volatile("s_waitcnt vmcnt(0)" ::: "memory");
      } else {
        // stage role: fetch slot s+2, commit slot s+1 into the idle LDS half
        const int mtu = (mt + 2) & 3;
        const int tu = t + (mt >> 1);          // mt>=2 -> next step
        if (tu < ZT){
          qwait(flags, bg, mtu, (u32)tu);
          const u64* src = (const u64*)(hbuf + qoff(tu & 1, bg, mtu, 0));
          if ((mt & 1) == 0){
            #pragma unroll
            for (int i = 0; i < 4; ++i){
              int cc = st + i * 256;
              vaE[i] = aload(src + (size_t)cc * 2);
              vbE[i] = aload(src + (size_t)cc * 2 + 1);
            }
          } else {
            #pragma unroll
            for (int i = 0; i < 4; ++i){
              int cc = st + i * 256;
              vaO[i] = aload(src + (size_t)cc * 2);
              vbO[i] = aload(src + (size_t)cc * 2 + 1);
            }
          }
        }
        if (!(t == ZT - 1 && mt == 3)){
          char* dst = (char*)hs2[(mt + 1) & 1];
          if ((mt & 1) == 0){
            #pragma unroll
            for (int i = 0; i < 4; ++i){
              int byte = (st + i * 256) * 16;
              int swz = byte ^ (((byte >> 5) & 3) << 4);
              *(s8v*)(dst + swz) = pair2v(vaO[i], vbO[i]);
            }
          } else {
            #pragma unroll
            for (int i = 0; i < 4; ++i){
              int byte = (st + i * 256) * 16;
              int swz = byte ^ (((byte >> 5) & 3) << 4);
              *(s8v*)(dst + swz) = pair2v(vaE[i], vbE[i]);
            }
          }
        }
      }
      __syncthreads();
      if (tid == 0)
        __hip_atomic_store(fl0 + (size_t)mt * 32 * 16, (u32)(t + 1),
                           __ATOMIC_RELAXED, __HIP_MEMORY_SCOPE_AGENT);
    }
  }

  // epilogue: hg==0 blocks compute out = h_T @ Wfc^T + bfc (h_T in buf 0)
  if (hg == 0){
    if (tid < 64){
      #pragma unroll
      for (int mt = 0; mt < 4; ++mt) qwait(flags, bg, mt, (u32)ZT);
    }
    __syncthreads();
    if (isC){
      float ob = (lr < ZNC) ? bfc[lr] : 0.f;
      f4v acc = {ob, ob, ob, ob};
      const u16* wp = Wfcb + (size_t)lr * ZH + lg * 8;
      #pragma unroll
      for (int kt = 0; kt < 16; ++kt){
        int hgp = 2 * kt + (lg >> 1);
        const u64* hp = (const u64*)(hbuf + qoff(0, bg, w, hgp));
        u64 a0 = aload(hp + lr * 4 + (lg & 1) * 2);
        u64 a1 = aload(hp + lr * 4 + (lg & 1) * 2 + 1);
        s8v av = pair2v(a0, a1);
        s8v bv = *(const s8v*)(wp + kt * 32);
        acc = __builtin_amdgcn_mfma_f32_16x16x32_bf16(av, bv, acc, 0, 0, 0);
      }
      if (lr < ZNC){
        #pragma unroll
        for (int r = 0; r < 4; ++r)
          out[(size_t)(bg * 64 + w * 16 + lg * 4 + r) * ZNC + lr] = acc[r];
      }
    }
  }
}

// ---------------------------------------------------------------------------
extern "C" void kernel_launch(void* const* d_in, const int* in_sizes, int n_in,
                              void* d_out, int out_size, void* d_ws, size_t ws_size,
                              hipStream_t stream)
{
  const float* seq  = (const float*)d_in[0];
  const float* W1   = (const float*)d_in[1];
  const float* b1   = (const float*)d_in[2];
  const float* W2   = (const float*)d_in[3];
  const float* b2   = (const float*)d_in[4];
  const float* W_ih = (const float*)d_in[5];
  const float* W_hh = (const float*)d_in[6];
  const float* b_ih = (const float*)d_in[7];
  const float* b_hh = (const float*)d_in[8];
  const float* Wfc  = (const float*)d_in[9];
  const float* bfc  = (const float*)d_in[10];
  float* out = (float*)d_out;

  char* ws = (char*)d_ws;
  size_t off = 0;
  auto alloc = [&](size_t bytes){ void* p = ws + off; off += (bytes + 255) & ~(size_t)255; return p; };
  u16*   Wc    = (u16*)  alloc((size_t)ZG * ZEH * 2);
  float* bc    = (float*)alloc((size_t)ZG * 4);
  u16*   Whh   = (u16*)  alloc((size_t)ZG * ZH * 2);
  u16*   Wfcb  = (u16*)  alloc((size_t)16 * ZH * 2);
  u16*   X1    = (u16*)  alloc((size_t)ZB * ZT * ZEH * 2);
  u16*   hbuf  = (u16*)  alloc((size_t)2 * ZB * ZH * 2);
  u32*   flags = (u32*)  alloc((size_t)8 * 4 * 32 * 16 * 4);  // 64B-padded per (bg,mt,hg)

  hipMemsetAsync(flags, 0, (size_t)8 * 4 * 32 * 16 * 4, stream);
  hipMemsetAsync(hbuf, 0, (size_t)ZB * ZH * 2, stream);      // h_0 = 0 (buffer 0)
  hipMemsetAsync(Wfcb, 0, (size_t)16 * ZH * 2, stream);      // pad rows 8..15 = 0

  hipLaunchKernelGGL(k_fold, dim3(ZG), dim3(128), 0, stream, W_ih, W2, b2, b_ih, b_hh, Wc, bc);
  hipLaunchKernelGGL(k_cvt, dim3((ZG * ZH + 255) / 256), dim3(256), 0, stream, W_hh, Whh, ZG * ZH);
  hipLaunchKernelGGL(k_cvt, dim3((ZNC * ZH + 255) / 256), dim3(256), 0, stream, Wfc, Wfcb, ZNC * ZH);
  hipLaunchKernelGGL(k_enc, dim3(ZB * ZT / 64), dim3(256), 0, stream, seq, W1, b1, X1);
  hipLaunchKernelGGL(k_lstm, dim3(NBLK), dim3(512), 0, stream,
                     X1, Whh, Wc, bc, Wfcb, bfc, hbuf, out, flags);
}